// Round 7
// baseline (339.826 us; speedup 1.0000x reference)
//
// R6 resubmit (3rd attempt of the same kernel). Rounds 5 and 6 both died
// with "MI355X container failed twice" — broker/infra failures with no
// compile log, no absmax, no counters. Before resubmitting I re-audited the
// kernel for anything that could kill a container (hang or GPU fault):
//   - no divergent __syncthreads (t/it loops are block-uniform; t==0 branch
//     is uniform),
//   - all global reads/writes bounds-checked: out max index 92159 < 92160,
//     x_idx max 2039 < 2048, W_comp idx in [0,45), bB-guarded loads,
//   - LDS = 63.9 KB < 160 KB; 512 thr = 8 waves, launch_bounds declared,
//   - no hipMalloc/Memcpy/sync in kernel_launch (graph-capture safe).
// Nothing kernel-side can explain the container deaths; the only prior infra
// failure (round 2) resolved on identical resubmit. Per rigor discipline the
// kernel is UNCHANGED so the standing prediction stays testable.
//
// THEORY (from R3 post-mortem): R3 measured 79.8 us, VALUBusy 23.9%,
// FETCH_SIZE 13.6 MB -> the 2x400x400 fp32 weight stream is L2-resident and
// per-call L2 traffic is 256 blocks x 13.1 MB = 2.62 GB ~= the 76 us L2-BW
// floor (34.5 TB/s). We sit on the L2 roofline, so the lever is cutting L2
// traffic, not latency/ILP. CHANGE vs R3: 2 batches per block (grid 128 x
// 512 thr, 8 waves/block, SQ_WAVES stays 1024). Each loaded W_lv element now
// feeds both batches from registers -> L2 traffic halves to 1.31 GB.
//
// PREDICTION: dur_us 48-62; FETCH_SIZE ~13.6 MB unchanged; VALUBusy 30-45%;
// SQ_WAVES 1024. Falsifier: dur >= 70 us with VALUBusy < 25% means sharing
// did not relieve L2 -> probe TCC_HIT/TCC_MISS next round. Fallback lever for
// R7: bf16-compressed weight copy staged in d_ws (another 2x traffic cut;
// accuracy margin: absmax 8e-3 vs threshold 4.5e-2).

#include <hip/hip_runtime.h>

#define kT 8
#define kG 120
#define kP 400
#define kObj 45
#define kS 10
#define kHid 200

// downsample map: streams at offsets [0,30,60,84,102], take first [10,10,8,6,6]
__device__ __constant__ int c_gmap[40] = {
    0,1,2,3,4,5,6,7,8,9,
    30,31,32,33,34,35,36,37,38,39,
    60,61,62,63,64,65,66,67,
    84,85,86,87,88,89,
    102,103,104,105,106,107};

__device__ __constant__ float c_freq[5] = {0.01f, 0.7f, 0.91f, 0.97f, 0.99f};

__device__ __forceinline__ float leaky_clamp(float x) {
    x = fminf(fmaxf(x, -1.0f), 1.0f);
    return x > 0.0f ? x : 0.01f * x;
}

// 2 batches per block; thread tid<400 owns output dim tid for BOTH batches.
__global__ __launch_bounds__(512) void tem_kernel(
    const float* __restrict__ g_seq, const int* __restrict__ x_idx,
    const float* __restrict__ W_comp, const float* __restrict__ W_repeat,
    const float* __restrict__ W_tile, const float* __restrict__ W_tile0,
    const float* __restrict__ w_x, const float* __restrict__ b_x,
    const float* __restrict__ W1, const float* __restrict__ b1,
    const float* __restrict__ W2, const float* __restrict__ b2,
    const float* __restrict__ W_lv1, const float* __restrict__ b_lv1,
    const float* __restrict__ W_lv2, const float* __restrict__ b_lv2,
    float* __restrict__ out, int Bn)
{
    const int tid = threadIdx.x;
    const int bA  = blockIdx.x * 2;      // first batch of this block
    const int bB  = bA + 1;              // second batch
    const bool hasB = (bB < Bn);
    const int dim = tid;
    const bool hasD = (tid < kP);
    const int wid  = tid >> 6;           // wave id 0..7
    const int lane = tid & 63;

    __shared__ float s_xflat[2][50];
    __shared__ float s_xc[2][kS];
    __shared__ float s_gdown[2][40];
    __shared__ float s_pinf[2][kP];
    __shared__ float s_h[2][kP];
    __shared__ float s_pt[2][kP];
    __shared__ float s_u[2][kT][kP];
    __shared__ float s_v[2][kT][kP];
    __shared__ float s_red[2][kT][8];
    __shared__ float s_dots[2][kT];
    __shared__ float s_coef[kT];
    __shared__ float s_xs[2][kS];
    __shared__ float s_hid[2][kHid];

    if (tid < 100) s_xflat[tid / 50][tid % 50] = 0.0f;
    __syncthreads();

    for (int t = 0; t < kT; ++t) {
        // ---- staging: one-hot gather + g downsample, both batches ----
        if (tid < kS) {
            int idx = x_idx[bA * kT + t];
            s_xc[0][tid] = W_comp[idx * kS + tid];
        } else if (tid >= 64 && tid < 64 + kS) {
            int idx = hasB ? x_idx[bB * kT + t] : 0;
            s_xc[1][tid - 64] = W_comp[idx * kS + (tid - 64)];
        } else if (tid >= 128 && tid < 168) {
            s_gdown[0][tid - 128] = g_seq[(bA * kT + t) * kG + c_gmap[tid - 128]];
        } else if (tid >= 192 && tid < 232) {
            s_gdown[1][tid - 192] = hasB ? g_seq[(bB * kT + t) * kG + c_gmap[tid - 192]] : 0.0f;
        } else if (tid == 511) {
            float c = 0.5f;
            for (int s = t - 1; s >= 0; --s) { s_coef[s] = c; c *= 0.9999f; }
        }
        __syncthreads();

        // ---- temporal filter ----
        if (tid < 50) {
            float f = c_freq[tid / 10];
            s_xflat[0][tid] = (1.0f - f) * s_xflat[0][tid] + f * s_xc[0][tid % 10];
        } else if (tid >= 64 && tid < 114) {
            int k = tid - 64;
            float f = c_freq[k / 10];
            s_xflat[1][k] = (1.0f - f) * s_xflat[1][k] + f * s_xc[1][k % 10];
        }
        __syncthreads();

        // ---- g_exp, x_exp, p_inf, h init (weights shared across batches) ----
        if (hasD) {
            float ge0 = 0.0f, ge1 = 0.0f;
            #pragma unroll
            for (int j = 0; j < 40; ++j) {
                float w = W_repeat[dim * 40 + j];
                ge0 += s_gdown[0][j] * w;
                ge1 += s_gdown[1][j] * w;
            }
            float xe0 = 0.0f, xe1 = 0.0f;
            #pragma unroll
            for (int j = 0; j < 50; ++j) {
                float w = W_tile[dim * 50 + j];
                xe0 += s_xflat[0][j] * w;
                xe1 += s_xflat[1][j] * w;
            }
            s_pinf[0][dim] = leaky_clamp(ge0 * xe0);
            s_h[0][dim]    = leaky_clamp(ge0);
            s_pinf[1][dim] = leaky_clamp(ge1 * xe1);
            s_h[1][dim]    = leaky_clamp(ge1);
        }
        __syncthreads();

        // ---- attractor: M applied as sum of <=t rank-1 terms ----
        if (t == 0) {
            if (hasD) {
                float h0 = s_h[0][dim], h1 = s_h[1][dim];
                #pragma unroll
                for (int it = 0; it < 5; ++it) {
                    h0 = leaky_clamp(0.8f * h0);
                    h1 = leaky_clamp(0.8f * h1);
                }
                s_h[0][dim] = h0;
                s_h[1][dim] = h1;
            }
            __syncthreads();
        } else {
            for (int it = 0; it < 5; ++it) {
                float h0 = hasD ? s_h[0][dim] : 0.0f;
                float h1 = hasD ? s_h[1][dim] : 0.0f;
                for (int s = 0; s < t; ++s) {
                    float p0 = hasD ? s_v[0][s][dim] * h0 : 0.0f;
                    float p1 = hasD ? s_v[1][s][dim] * h1 : 0.0f;
                    #pragma unroll
                    for (int off = 32; off; off >>= 1) {
                        p0 += __shfl_down(p0, off, 64);
                        p1 += __shfl_down(p1, off, 64);
                    }
                    if (lane == 0) { s_red[0][s][wid] = p0; s_red[1][s][wid] = p1; }
                }
                __syncthreads();
                if (tid < t) {
                    float d = 0.0f;
                    #pragma unroll
                    for (int w = 0; w < 8; ++w) d += s_red[0][tid][w];
                    s_dots[0][tid] = d;
                } else if (tid >= 64 && tid < 64 + t) {
                    float d = 0.0f;
                    #pragma unroll
                    for (int w = 0; w < 8; ++w) d += s_red[1][tid - 64][w];
                    s_dots[1][tid - 64] = d;
                }
                __syncthreads();
                if (hasD) {
                    float mh0 = 0.0f, mh1 = 0.0f;
                    for (int s = 0; s < t; ++s) {
                        mh0 += s_coef[s] * s_dots[0][s] * s_u[0][s][dim];
                        mh1 += s_coef[s] * s_dots[1][s] * s_u[1][s][dim];
                    }
                    s_h[0][dim] = leaky_clamp(0.8f * h0 + mh0);
                    s_h[1][dim] = leaky_clamp(0.8f * h1 + mh1);
                }
                __syncthreads();
            }
        }

        // ---- precision matvecs: weight loads shared across both batches ----
        if (hasD) {
            float A10 = 0.f, A11 = 0.f, A20 = 0.f, A21 = 0.f;   // lv1
            float B10 = 0.f, B11 = 0.f, B20 = 0.f, B21 = 0.f;   // lv2
            const float* w1p = W_lv1 + dim;
            const float* w2p = W_lv2 + dim;
            #pragma unroll 4
            for (int j = 0; j < kP; j += 2) {
                float w1a = w1p[j * kP],       w2a = w2p[j * kP];
                float w1b = w1p[(j + 1) * kP], w2b = w2p[(j + 1) * kP];
                float pi0a = s_pinf[0][j], pi0b = s_pinf[0][j + 1];
                float pr0a = s_h[0][j],    pr0b = s_h[0][j + 1];
                float pi1a = s_pinf[1][j], pi1b = s_pinf[1][j + 1];
                float pr1a = s_h[1][j],    pr1b = s_h[1][j + 1];
                A10 += pi0a * w1a; A11 += pi0b * w1b;
                A20 += pi1a * w1a; A21 += pi1b * w1b;
                B10 += pr0a * w2a; B11 += pr0b * w2b;
                B20 += pr1a * w2a; B21 += pr1b * w2b;
            }
            float bl1 = b_lv1[dim], bl2 = b_lv2[dim];
            {   // fusion batch 0
                float lv1 = -2.0f + 6.0f * tanhf((A10 + A11 + bl1) * (1.0f / 6.0f));
                float lv2 = -2.0f + 6.0f * tanhf((B10 + B11 + bl2) * (1.0f / 6.0f));
                float inv1 = expf(-lv1), inv2 = expf(-lv2);
                float pr = s_h[0][dim];
                float p  = (s_pinf[0][dim] * inv1 + pr * inv2) / (inv1 + inv2);
                s_pt[0][dim] = p;
                s_u[0][t][dim] = p - pr;
                s_v[0][t][dim] = p + pr;
            }
            {   // fusion batch 1
                float lv1 = -2.0f + 6.0f * tanhf((A20 + A21 + bl1) * (1.0f / 6.0f));
                float lv2 = -2.0f + 6.0f * tanhf((B20 + B21 + bl2) * (1.0f / 6.0f));
                float inv1 = expf(-lv1), inv2 = expf(-lv2);
                float pr = s_h[1][dim];
                float p  = (s_pinf[1][dim] * inv1 + pr * inv2) / (inv1 + inv2);
                s_pt[1][dim] = p;
                s_u[1][t][dim] = p - pr;
                s_v[1][t][dim] = p + pr;
            }
        }
        __syncthreads();

        // ---- generative decode, both batches ----
        if (tid < kS) {
            float acc = 0.0f;
            for (int j = 0; j < 100; ++j)
                acc += s_pt[0][j] * W_tile0[j * kS + tid];
            s_xs[0][tid] = w_x[0] * acc + b_x[tid];
        } else if (tid >= 64 && tid < 64 + kS) {
            int k = tid - 64;
            float acc = 0.0f;
            for (int j = 0; j < 100; ++j)
                acc += s_pt[1][j] * W_tile0[j * kS + k];
            s_xs[1][k] = w_x[0] * acc + b_x[k];
        }
        __syncthreads();
        if (tid < kHid) {
            float acc = b1[tid];
            #pragma unroll
            for (int d = 0; d < kS; ++d)
                acc += s_xs[0][d] * W1[d * kHid + tid];
            s_hid[0][tid] = acc > 0.0f ? acc : (expf(acc) - 1.0f);
        } else if (tid >= 256 && tid < 256 + kHid) {
            int k = tid - 256;
            float acc = b1[k];
            #pragma unroll
            for (int d = 0; d < kS; ++d)
                acc += s_xs[1][d] * W1[d * kHid + k];
            s_hid[1][k] = acc > 0.0f ? acc : (expf(acc) - 1.0f);
        }
        __syncthreads();
        if (tid < kObj) {
            float acc = b2[tid];
            for (int h = 0; h < kHid; ++h)
                acc += s_hid[0][h] * W2[h * kObj + tid];
            out[(bA * kT + t) * kObj + tid] = acc;
        } else if (tid >= 256 && tid < 256 + kObj) {
            int k = tid - 256;
            float acc = b2[k];
            for (int h = 0; h < kHid; ++h)
                acc += s_hid[1][h] * W2[h * kObj + k];
            if (hasB) out[(bB * kT + t) * kObj + k] = acc;
        }
        __syncthreads();
    }
}

extern "C" void kernel_launch(void* const* d_in, const int* in_sizes, int n_in,
                              void* d_out, int out_size, void* d_ws, size_t ws_size,
                              hipStream_t stream) {
    const float* g_seq   = (const float*)d_in[0];
    const int*   x_idx   = (const int*)d_in[1];
    const float* W_comp  = (const float*)d_in[2];
    const float* W_repeat= (const float*)d_in[3];
    const float* W_tile  = (const float*)d_in[4];
    const float* W_tile0 = (const float*)d_in[5];
    const float* w_x     = (const float*)d_in[6];
    const float* b_x     = (const float*)d_in[7];
    const float* W1      = (const float*)d_in[8];
    const float* b1      = (const float*)d_in[9];
    const float* W2      = (const float*)d_in[10];
    const float* b2      = (const float*)d_in[11];
    const float* W_lv1   = (const float*)d_in[12];
    const float* b_lv1   = (const float*)d_in[13];
    const float* W_lv2   = (const float*)d_in[14];
    const float* b_lv2   = (const float*)d_in[15];
    float* out = (float*)d_out;

    const int Bn = in_sizes[0] / (kT * kG);
    const int nBlocks = (Bn + 1) / 2;
    tem_kernel<<<dim3(nBlocks), dim3(512), 0, stream>>>(
        g_seq, x_idx, W_comp, W_repeat, W_tile, W_tile0, w_x, b_x,
        W1, b1, W2, b2, W_lv1, b_lv1, W_lv2, b_lv2, out, Bn);
}

// Round 8
// 328.008 us; speedup vs baseline: 1.0360x; 1.0360x over previous
//
// R8: 256 blocks x 512 threads, 1 batch/block, 1 output-dim/thread.
// Theory: latency-bound (R4/R7 disproved L2-BW-bound: traffic halved, time x3.5,
// VALUBusy fell to 10.6%). Lever = wave parallelism (8 waves/CU, 256 CUs) and
// halved per-wave serial work; 8 independent FMA chains in the matvec.
#include <hip/hip_runtime.h>

#define kT 8
#define kG 120
#define kP 400
#define kObj 45
#define kS 10
#define kHid 200

__device__ __constant__ int c_gmap[40] = {
    0,1,2,3,4,5,6,7,8,9,
    30,31,32,33,34,35,36,37,38,39,
    60,61,62,63,64,65,66,67,
    84,85,86,87,88,89,
    102,103,104,105,106,107};

__device__ __constant__ float c_freq[5] = {0.01f, 0.7f, 0.91f, 0.97f, 0.99f};

__device__ __forceinline__ float leaky_clamp(float x) {
    x = fminf(fmaxf(x, -1.0f), 1.0f);
    return x > 0.0f ? x : 0.01f * x;
}

__global__ __launch_bounds__(512) void tem_kernel(
    const float* __restrict__ g_seq, const int* __restrict__ x_idx,
    const float* __restrict__ W_comp, const float* __restrict__ W_repeat,
    const float* __restrict__ W_tile, const float* __restrict__ W_tile0,
    const float* __restrict__ w_x, const float* __restrict__ b_x,
    const float* __restrict__ W1, const float* __restrict__ b1,
    const float* __restrict__ W2, const float* __restrict__ b2,
    const float* __restrict__ W_lv1, const float* __restrict__ b_lv1,
    const float* __restrict__ W_lv2, const float* __restrict__ b_lv2,
    float* __restrict__ out)
{
    const int b   = blockIdx.x;
    const int tid = threadIdx.x;
    const int dim = tid;
    const bool hasD = (tid < kP);
    const int wid  = tid >> 6;          // wave 0..7; dims live in waves 0..6
    const int lane = tid & 63;

    __shared__ float s_xflat[50];
    __shared__ float s_xc[kS];
    __shared__ float s_gdown[40];
    __shared__ float s_pinf[kP];
    __shared__ float s_h[kP];
    __shared__ float s_pt[kP];
    __shared__ float s_u[kT][kP];
    __shared__ float s_v[kT][kP];
    __shared__ float s_red[kT][8];      // per-wave dot partials (waves 0..6 used)
    __shared__ float s_dots[kT];
    __shared__ float s_coef[kT];
    __shared__ float s_xs[kS];
    __shared__ float s_hid[kHid];

    if (tid < 50) s_xflat[tid] = 0.0f;
    __syncthreads();

    for (int t = 0; t < kT; ++t) {
        // ---- staging: one-hot gather, g downsample, Hebbian coefs ----
        if (tid < kS) {
            int idx = x_idx[b * kT + t];
            s_xc[tid] = W_comp[idx * kS + tid];
        } else if (tid >= 64 && tid < 104) {
            s_gdown[tid - 64] = g_seq[(b * kT + t) * kG + c_gmap[tid - 64]];
        } else if (tid == 128) {
            float c = 0.5f;
            for (int s = t - 1; s >= 0; --s) { s_coef[s] = c; c *= 0.9999f; }
        }
        __syncthreads();

        // ---- temporal filter ----
        if (tid < 50) {
            float f = c_freq[tid / 10];
            s_xflat[tid] = (1.0f - f) * s_xflat[tid] + f * s_xc[tid % 10];
        }
        __syncthreads();

        // ---- g_exp, x_exp, p_inf, h init (1 dim per thread) ----
        if (hasD) {
            float ge = 0.0f;
            #pragma unroll
            for (int j = 0; j < 40; ++j)
                ge += s_gdown[j] * W_repeat[dim * 40 + j];
            float xe = 0.0f;
            #pragma unroll
            for (int j = 0; j < 50; ++j)
                xe += s_xflat[j] * W_tile[dim * 50 + j];
            s_pinf[dim] = leaky_clamp(ge * xe);
            s_h[dim]    = leaky_clamp(ge);
        }
        __syncthreads();

        // ---- attractor: M applied as sum of <=t rank-1 terms ----
        if (t == 0) {
            if (hasD) {
                float h = s_h[dim];
                #pragma unroll
                for (int it = 0; it < 5; ++it) h = leaky_clamp(0.8f * h);
                s_h[dim] = h;
            }
            __syncthreads();
        } else {
            for (int it = 0; it < 5; ++it) {
                float h = hasD ? s_h[dim] : 0.0f;
                for (int s = 0; s < t; ++s) {
                    float p = hasD ? s_v[s][dim] * h : 0.0f;
                    #pragma unroll
                    for (int off = 32; off; off >>= 1) p += __shfl_down(p, off, 64);
                    if (lane == 0 && wid < 7) s_red[s][wid] = p;
                }
                __syncthreads();
                if (tid < t) {
                    float d = 0.0f;
                    #pragma unroll
                    for (int w = 0; w < 7; ++w) d += s_red[tid][w];
                    s_dots[tid] = d;
                }
                __syncthreads();
                if (hasD) {
                    float mh = 0.0f;
                    for (int s = 0; s < t; ++s)
                        mh += s_coef[s] * s_dots[s] * s_u[s][dim];
                    s_h[dim] = leaky_clamp(0.8f * h + mh);
                }
                __syncthreads();
            }
        }

        // ---- precision matvecs: 1 dim/thread, 8 independent chains ----
        if (hasD) {
            const float* w1 = W_lv1 + dim;
            const float* w2 = W_lv2 + dim;
            float a0 = 0.f, a1 = 0.f, a2 = 0.f, a3 = 0.f;   // lv1
            float c0 = 0.f, c1 = 0.f, c2 = 0.f, c3 = 0.f;   // lv2
            #pragma unroll 2
            for (int j = 0; j < kP; j += 4) {
                float pi0 = s_pinf[j],   pr0 = s_h[j];
                float pi1 = s_pinf[j+1], pr1 = s_h[j+1];
                float pi2 = s_pinf[j+2], pr2 = s_h[j+2];
                float pi3 = s_pinf[j+3], pr3 = s_h[j+3];
                a0 += pi0 * w1[(j+0) * kP];
                a1 += pi1 * w1[(j+1) * kP];
                a2 += pi2 * w1[(j+2) * kP];
                a3 += pi3 * w1[(j+3) * kP];
                c0 += pr0 * w2[(j+0) * kP];
                c1 += pr1 * w2[(j+1) * kP];
                c2 += pr2 * w2[(j+2) * kP];
                c3 += pr3 * w2[(j+3) * kP];
            }
            float lv1 = -2.0f + 6.0f * tanhf((a0 + a1 + a2 + a3 + b_lv1[dim]) * (1.0f / 6.0f));
            float lv2 = -2.0f + 6.0f * tanhf((c0 + c1 + c2 + c3 + b_lv2[dim]) * (1.0f / 6.0f));
            float inv1 = expf(-lv1), inv2 = expf(-lv2);
            float pr = s_h[dim];
            float p  = (s_pinf[dim] * inv1 + pr * inv2) / (inv1 + inv2);
            s_pt[dim] = p;
            s_u[t][dim] = p - pr;
            s_v[t][dim] = p + pr;
        }
        __syncthreads();

        // ---- generative decode ----
        if (tid < kS) {
            float acc = 0.0f;
            for (int j = 0; j < 100; ++j)
                acc += s_pt[j] * W_tile0[j * kS + tid];
            s_xs[tid] = w_x[0] * acc + b_x[tid];
        }
        __syncthreads();
        if (tid < kHid) {
            float acc = b1[tid];
            #pragma unroll
            for (int d = 0; d < kS; ++d)
                acc += s_xs[d] * W1[d * kHid + tid];
            s_hid[tid] = acc > 0.0f ? acc : (expf(acc) - 1.0f);
        }
        __syncthreads();
        if (tid < kObj) {
            float acc = b2[tid];
            for (int h = 0; h < kHid; ++h)
                acc += s_hid[h] * W2[h * kObj + tid];
            out[(b * kT + t) * kObj + tid] = acc;
        }
        __syncthreads();
    }
}

extern "C" void kernel_launch(void* const* d_in, const int* in_sizes, int n_in,
                              void* d_out, int out_size, void* d_ws, size_t ws_size,
                              hipStream_t stream) {
    const float* g_seq   = (const float*)d_in[0];
    const int*   x_idx   = (const int*)d_in[1];
    const float* W_comp  = (const float*)d_in[2];
    const float* W_repeat= (const float*)d_in[3];
    const float* W_tile  = (const float*)d_in[4];
    const float* W_tile0 = (const float*)d_in[5];
    const float* w_x     = (const float*)d_in[6];
    const float* b_x     = (const float*)d_in[7];
    const float* W1      = (const float*)d_in[8];
    const float* b1      = (const float*)d_in[9];
    const float* W2      = (const float*)d_in[10];
    const float* b2      = (const float*)d_in[11];
    const float* W_lv1   = (const float*)d_in[12];
    const float* b_lv1   = (const float*)d_in[13];
    const float* W_lv2   = (const float*)d_in[14];
    const float* b_lv2   = (const float*)d_in[15];
    float* out = (float*)d_out;

    const int Bn = in_sizes[0] / (kT * kG);
    tem_kernel<<<dim3(Bn), dim3(512), 0, stream>>>(
        g_seq, x_idx, W_comp, W_repeat, W_tile, W_tile0, w_x, b_x,
        W1, b1, W2, b2, W_lv1, b_lv1, W_lv2, b_lv2, out);
}